// Round 3
// baseline (1125.458 us; speedup 1.0000x reference)
//
#include <hip/hip_runtime.h>

// ---------------- types & helpers ----------------
typedef __bf16 bf16x8 __attribute__((ext_vector_type(8)));
typedef float  f32x4  __attribute__((ext_vector_type(4)));

__device__ __forceinline__ unsigned short f2bf(float f) {
    unsigned u = __float_as_uint(f);
    u += 0x7fffu + ((u >> 16) & 1u);   // RNE
    return (unsigned short)(u >> 16);
}

__device__ __forceinline__ void gld_lds16(const void* g, void* l) {
    __builtin_amdgcn_global_load_lds(
        (const __attribute__((address_space(1))) void*)g,
        (__attribute__((address_space(3))) void*)l,
        16, 0, 0);
}

#define WAITVM(N) asm volatile("s_waitcnt vmcnt(" #N ")" ::: "memory")
#define SB0()     __builtin_amdgcn_sched_barrier(0)
#define BAR()     __builtin_amdgcn_s_barrier()

// ---------------- problem constants ----------------
#define NB  32
#define SQ  256
#define HD  1024
#define ID  4096
#define NEXP 8          // skill experts; index 8 = shared
#define PAIRS (NB * 3)  // (batch, slot) pairs

// workspace layout (bytes)
#define OFF_EID    ((size_t)0)            // 96 int
#define OFF_WGT    ((size_t)512)          // 96 float
#define OFF_XBF    ((size_t)1024)                       // 8192*1024 bf16
#define OFF_GATET  (OFF_XBF   + (size_t)16777216)       // 9*4096*1024 bf16
#define OFF_UPT    (OFF_GATET + (size_t)75497472)
#define OFF_DOWNT  (OFF_UPT   + (size_t)75497472)
#define OFF_ACT    (OFF_DOWNT + (size_t)75497472)       // 96*256*4096 bf16
// stage2 z=1 partial (fp32, 32 MB) aliases gateT (dead after stage1)

// pair order sorted by expert id (locality for weight reuse)
__device__ int d_sord[PAIRS];

// ---------------- routing ----------------
__global__ void routing_kernel(const float* __restrict__ logits,
                               int* __restrict__ eid, float* __restrict__ wgt) {
    int b = threadIdx.x;
    if (b < NB) {
        float l[NEXP];
        for (int j = 0; j < NEXP; ++j) l[j] = logits[b * NEXP + j];
        int a0 = 0;
        for (int j = 1; j < NEXP; ++j) if (l[j] > l[a0]) a0 = j;
        int a1 = -1;
        for (int j = 0; j < NEXP; ++j) {
            if (j == a0) continue;
            if (a1 < 0 || l[j] > l[a1]) a1 = j;
        }
        float w0 = 1.0f / (1.0f + expf(l[a1] - l[a0]));
        eid[b * 3 + 0] = a0;  wgt[b * 3 + 0] = w0;
        eid[b * 3 + 1] = a1;  wgt[b * 3 + 1] = 1.0f - w0;
        eid[b * 3 + 2] = NEXP; wgt[b * 3 + 2] = 1.0f;   // shared
    }
    __syncthreads();
    if (threadIdx.x == 0) {
        int cnt[NEXP + 2];
        for (int i = 0; i < NEXP + 2; ++i) cnt[i] = 0;
        for (int i = 0; i < PAIRS; ++i) cnt[eid[i] + 1]++;
        for (int e = 0; e < NEXP + 1; ++e) cnt[e + 1] += cnt[e];
        for (int i = 0; i < PAIRS; ++i) d_sord[cnt[eid[i]]++] = i;
    }
}

// ---------------- x fp32 -> bf16 ----------------
__global__ void xcvt_kernel(const float* __restrict__ x,
                            unsigned short* __restrict__ xb, int n4) {
    int i = blockIdx.x * 256 + threadIdx.x;
    if (i < n4) {
        float4 v = ((const float4*)x)[i];
        union { unsigned short s[4]; uint2 u; } p;
        p.s[0] = f2bf(v.x); p.s[1] = f2bf(v.y);
        p.s[2] = f2bf(v.z); p.s[3] = f2bf(v.w);
        ((uint2*)xb)[i] = p.u;
    }
}

// ---------------- weight transpose+convert: [R][C] fp32 -> [C][R] bf16 ----------------
__global__ void transpose_cvt(const float* __restrict__ skill,
                              const float* __restrict__ shared_m,
                              unsigned short* __restrict__ out, int R, int C) {
    const int e = blockIdx.z;                       // 0..8
    const float* src = (e < NEXP) ? (skill + (size_t)e * R * C) : shared_m;
    unsigned short* dst = out + (size_t)e * R * C;  // [C][R]
    const int c0 = blockIdx.x * 64;
    const int r0 = blockIdx.y * 64;
    __shared__ unsigned short t[64][66];
    const int tid = threadIdx.x;
    const int lr = tid >> 4;            // 0..15
    const int lc = (tid & 15) * 4;
    for (int it = 0; it < 4; ++it) {
        int r = lr + it * 16;
        float4 v = *(const float4*)(src + (size_t)(r0 + r) * C + c0 + lc);
        t[r][lc + 0] = f2bf(v.x);
        t[r][lc + 1] = f2bf(v.y);
        t[r][lc + 2] = f2bf(v.z);
        t[r][lc + 3] = f2bf(v.w);
    }
    __syncthreads();
    const int oc = tid >> 2;            // out row (original col), 0..63
    const int k0 = (tid & 3) * 16;      // 16 elems along original rows
    unsigned int pk[8];
    for (int j = 0; j < 8; ++j) {
        unsigned int lo = t[k0 + 2 * j + 0][oc];
        unsigned int hi = t[k0 + 2 * j + 1][oc];
        pk[j] = lo | (hi << 16);
    }
    unsigned short* dp = dst + (size_t)(c0 + oc) * R + r0 + k0;
    ((uint4*)dp)[0] = make_uint4(pk[0], pk[1], pk[2], pk[3]);
    ((uint4*)dp)[1] = make_uint4(pk[4], pk[5], pk[6], pk[7]);
}

// shared phase macros (acc[8][4], av[4], bv[4], Lc, rdA, rdB defined in kernel)
#define LDFRAGS(KH, MB)                                                      \
    _Pragma("unroll") for (int i2 = 0; i2 < 4; ++i2)                         \
        av[i2] = *(const bf16x8*)(Lc + (KH) + rdA + ((MB) + i2) * 512);
#define LDBFRAGS(KH)                                                         \
    _Pragma("unroll") for (int i2 = 0; i2 < 4; ++i2)                         \
        bv[i2] = *(const bf16x8*)(Lc + (KH) + rdB + i2 * 512);
#define DOMFMA(MB)                                                           \
    __builtin_amdgcn_s_setprio(1);                                           \
    _Pragma("unroll") for (int mi = 0; mi < 4; ++mi)                         \
        _Pragma("unroll") for (int ni = 0; ni < 4; ++ni)                     \
            acc[(MB) + mi][ni] = __builtin_amdgcn_mfma_f32_16x16x32_bf16(    \
                av[mi], bv[ni], acc[(MB) + mi][ni], 0, 0, 0);                \
    __builtin_amdgcn_s_setprio(0);

// =====================================================================
// stage1: act = gelu(x@gate) * (x@up) * w  (bf16 out)
// m201-style: BM=256 (all tokens) x BN=128 I-cols x {G,U}, BK=64.
// 8 waves 2Mx4N, wave-tile 128 rows x 32 I-cols x {G,U} (acc 8x4 f32x4).
// LDS 128 KiB: 2 buf x (A[2kh][256][32] + B[2kh][256][32]).
// 4 phases/K-tile, counted vmcnt(4) at P2/P4, distance-1 tile prefetch.
// B rows interleave G/U in 32-row blocks so gelu pairing is lane-local.
// =====================================================================
__global__ __launch_bounds__(512, 2) void stage1_gateup(
    const unsigned short* __restrict__ xbf,     // [8192][1024]
    const unsigned short* __restrict__ gateT,   // [9][4096][1024]
    const unsigned short* __restrict__ upT,
    const int* __restrict__ eid, const float* __restrict__ wgt,
    unsigned short* __restrict__ act)           // [96][256][4096]
{
    extern __shared__ unsigned short lds[];     // 2 x 32768 shorts = 128 KiB

    // locality: XCD g owns 12 sorted pairs; subgroups of 4 pairs, nt outer
    const int bid = blockIdx.x;                 // 0..3071
    const int g   = bid & 7;
    const int r0_ = bid >> 3;                   // 0..383
    const int sg  = r0_ >> 7;                   // 0..2
    const int rr  = r0_ & 127;
    const int nt  = rr >> 2;                    // 0..31 (I tile of 128)
    const int pi  = rr & 3;
    const int p   = d_sord[g * 12 + sg * 4 + pi];
    const int b   = p / 3;
    const int e   = eid[p];
    const float wS = wgt[p];

    const int tid  = threadIdx.x;
    const int wv   = tid >> 6;
    const int lane = tid & 63;
    const int wr   = wv >> 2;          // 0..1 : M half (128 rows)
    const int wc   = wv & 3;           // 0..3 : 32-I-col slice
    const int lrow = lane & 15;
    const int chunk = lane >> 4;       // 0..3 (8-short k-chunk)
    const int lr4  = lane >> 2;

    // staging: lane l writes LDS row (l>>2), chunk (l&3); source chunk pre-swizzled
    const int stc8 = (((lane & 3) ^ ((lane >> 2) & 3)) << 3);
    const int dA   = (wv * 2) * 512;   // shorts; q adds 512

    const unsigned short* pa[2];
    const unsigned short* pb[2];
#pragma unroll
    for (int q = 0; q < 2; ++q) {
        const int seg = wv * 2 + q;    // 16-row segment
        pa[q] = xbf + ((size_t)(b * SQ + seg * 16 + lr4)) * HD + stc8;
        const int s    = (seg >> 1) & 1;                       // 0=G 1=U
        const int icol = nt * 128 + (seg >> 2) * 32 + (seg & 1) * 16 + lr4;
        pb[q] = (s ? upT : gateT) + ((size_t)e * ID + icol) * HD + stc8;
    }

    // frag-read offsets (shorts); swizzle chunk ^ (row&3)
    const int rdA = (wr * 128 + lrow) * 32 + ((chunk ^ (lrow & 3)) << 3);
    const int rdB = 16384 + (wc * 64 + lrow) * 32 + ((chunk ^ (lrow & 3)) << 3);

    f32x4 acc[8][4];
#pragma unroll
    for (int i = 0; i < 8; ++i)
#pragma unroll
        for (int j = 0; j < 4; ++j) acc[i][j] = (f32x4)0.f;

    // prologue: stage tile 0 into buf 0, order Ak0,Bk0,Ak1,Bk1
    {
        unsigned short* L0 = lds;
        gld_lds16(pa[0],      L0 +          dA);
        gld_lds16(pa[1],      L0 +          dA + 512);
        gld_lds16(pb[0],      L0 + 16384 +  dA);
        gld_lds16(pb[1],      L0 + 16384 +  dA + 512);
        gld_lds16(pa[0] + 32, L0 +  8192 +  dA);
        gld_lds16(pa[1] + 32, L0 +  8192 +  dA + 512);
        gld_lds16(pb[0] + 32, L0 + 24576 +  dA);
        gld_lds16(pb[1] + 32, L0 + 24576 +  dA + 512);
        SB0(); WAITVM(4); SB0();
        BAR();
    }

    const int NT = HD / 64;   // 16
#pragma unroll 1
    for (int t = 0; t < NT; ++t) {
        unsigned short* Lc = lds + (t & 1) * 32768;
        unsigned short* Ln = lds + ((t & 1) ^ 1) * 32768;
        const bool pf = (t + 1 < NT);
        const int kof = (t + 1) * 64;
        bf16x8 av[4], bv[4];

        // ---- P1: (M0, kh0) ---- stage A-kh0(t+1)
        LDFRAGS(0, 0); LDBFRAGS(0);
        if (pf) { gld_lds16(pa[0] + kof, Ln + dA); gld_lds16(pa[1] + kof, Ln + dA + 512); }
        BAR();
        DOMFMA(0);
        BAR();

        // ---- P2: (M1, kh0) ---- stage B-kh0(t+1); wait for {A-kh1,B-kh1}(t)
        LDFRAGS(0, 4);
        if (pf) { gld_lds16(pb[0] + kof, Ln + 16384 + dA); gld_lds16(pb[1] + kof, Ln + 16384 + dA + 512); }
        SB0();
        if (pf) { WAITVM(4); } else { WAITVM(0); }
        SB0();
        BAR();
        DOMFMA(4);
        BAR();

        // ---- P3: (M0, kh1) ---- stage A-kh1(t+1)
        LDFRAGS(8192, 0); LDBFRAGS(8192);
        if (pf) { gld_lds16(pa[0] + kof + 32, Ln + 8192 + dA); gld_lds16(pa[1] + kof + 32, Ln + 8192 + dA + 512); }
        BAR();
        DOMFMA(0);
        BAR();

        // ---- P4: (M1, kh1) ---- stage B-kh1(t+1); wait for {A-kh0,B-kh0}(t+1)
        LDFRAGS(8192, 4);
        if (pf) {
            gld_lds16(pb[0] + kof + 32, Ln + 24576 + dA);
            gld_lds16(pb[1] + kof + 32, Ln + 24576 + dA + 512);
            SB0(); WAITVM(4); SB0();
        }
        BAR();
        DOMFMA(4);
        BAR();
    }

    // epilogue: gelu(g)*u*w -> bf16 (acc[.][0,1]=G, acc[.][2,3]=U, same I-cols)
    unsigned short* actp = act + (size_t)p * (SQ * ID);
    const int rb = wr * 128 + (chunk << 2);
    const int cb = nt * 128 + wc * 32 + lrow;
#pragma unroll
    for (int mf = 0; mf < 8; ++mf)
#pragma unroll
        for (int pp = 0; pp < 2; ++pp)
#pragma unroll
            for (int r2 = 0; r2 < 4; ++r2) {
                float gv = acc[mf][pp][r2];
                float uv = acc[mf][pp + 2][r2];
                float t2 = -1.5957691216057308f * gv * (1.0f + 0.044715f * gv * gv);
                float h  = __fdividef(gv, 1.0f + __expf(t2)) * uv * wS;
                actp[(size_t)(rb + mf * 16 + r2) * ID + cb + pp * 16] = f2bf(h);
            }
}

// =====================================================================
// stage2: out = sum_slot act_slot @ down_slot  (fp32)
// Same 4-phase template. BM=256, BN=256 H-cols, K split in 2 (z=0/1,
// 96 K-tiles each). Grid 256 = 1 block/CU. z=1 -> fp32 partial.
// =====================================================================
__global__ __launch_bounds__(512, 2) void stage2_down(
    const unsigned short* __restrict__ act,     // [96][256][4096]
    const unsigned short* __restrict__ downT,   // [9][1024][4096]
    const int* __restrict__ eid,
    float* __restrict__ out,                    // [32][256][1024]
    float* __restrict__ part1)                  // z=1 partial
{
    extern __shared__ unsigned short lds[];

    const int lid = blockIdx.x;                 // 0..255
    const int sw  = (lid & 7) * 32 + (lid >> 3);
    const int z   = sw >> 7;                    // K half
    const int q7  = sw & 127;
    const int b   = q7 >> 2;
    const int ntH = q7 & 3;                     // 256-wide H tile
    const int b3  = b * 3;
    const int e0 = eid[b3], e1 = eid[b3 + 1], e2 = eid[b3 + 2];

    const int tid  = threadIdx.x;
    const int wv   = tid >> 6;
    const int lane = tid & 63;
    const int wr   = wv >> 2;
    const int wc   = wv & 3;
    const int lrow = lane & 15;
    const int chunk = lane >> 4;
    const int lr4  = lane >> 2;
    const int stc8 = (((lane & 3) ^ ((lane >> 2) & 3)) << 3);
    const int dA   = (wv * 2) * 512;

    const int rdA = (wr * 128 + lrow) * 32 + ((chunk ^ (lrow & 3)) << 3);
    const int rdB = 16384 + (wc * 64 + lrow) * 32 + ((chunk ^ (lrow & 3)) << 3);

    f32x4 acc[8][4];
#pragma unroll
    for (int i = 0; i < 8; ++i)
#pragma unroll
        for (int j = 0; j < 4; ++j) acc[i][j] = (f32x4)0.f;

    // per-K-tile source bases (gk = z*96 + tile index)
    auto mksrc = [&](int gk, const unsigned short*& a0, const unsigned short*& a1,
                     const unsigned short*& b0, const unsigned short*& b1) {
        const int slot = gk >> 6;
        const int i0   = (gk & 63) << 6;
        const int esl  = (slot == 0) ? e0 : ((slot == 1) ? e1 : e2);
        a0 = act + ((size_t)((b3 + slot) * SQ) + wv * 32 + lr4) * ID + i0 + stc8;
        a1 = a0 + (size_t)16 * ID;
        b0 = downT + ((size_t)esl * HD + ntH * 256 + wv * 32 + lr4) * ID + i0 + stc8;
        b1 = b0 + (size_t)16 * ID;
    };

    // prologue: tile 0 -> buf 0
    {
        const unsigned short *a0, *a1, *b0, *b1;
        mksrc(z * 96, a0, a1, b0, b1);
        unsigned short* L0 = lds;
        gld_lds16(a0,      L0 +          dA);
        gld_lds16(a1,      L0 +          dA + 512);
        gld_lds16(b0,      L0 + 16384 +  dA);
        gld_lds16(b1,      L0 + 16384 +  dA + 512);
        gld_lds16(a0 + 32, L0 +  8192 +  dA);
        gld_lds16(a1 + 32, L0 +  8192 +  dA + 512);
        gld_lds16(b0 + 32, L0 + 24576 +  dA);
        gld_lds16(b1 + 32, L0 + 24576 +  dA + 512);
        SB0(); WAITVM(4); SB0();
        BAR();
    }

    const int NT = 96;
#pragma unroll 1
    for (int t = 0; t < NT; ++t) {
        unsigned short* Lc = lds + (t & 1) * 32768;
        unsigned short* Ln = lds + ((t & 1) ^ 1) * 32768;
        const bool pf = (t + 1 < NT);
        const unsigned short *a0 = nullptr, *a1 = nullptr, *b0 = nullptr, *b1 = nullptr;
        if (pf) mksrc(z * 96 + t + 1, a0, a1, b0, b1);
        bf16x8 av[4], bv[4];

        // ---- P1 ----
        LDFRAGS(0, 0); LDBFRAGS(0);
        if (pf) { gld_lds16(a0, Ln + dA); gld_lds16(a1, Ln + dA + 512); }
        BAR();
        DOMFMA(0);
        BAR();

        // ---- P2 ----
        LDFRAGS(0, 4);
        if (pf) { gld_lds16(b0, Ln + 16384 + dA); gld_lds16(b1, Ln + 16384 + dA + 512); }
        SB0();
        if (pf) { WAITVM(4); } else { WAITVM(0); }
        SB0();
        BAR();
        DOMFMA(4);
        BAR();

        // ---- P3 ----
        LDFRAGS(8192, 0); LDBFRAGS(8192);
        if (pf) { gld_lds16(a0 + 32, Ln + 8192 + dA); gld_lds16(a1 + 32, Ln + 8192 + dA + 512); }
        BAR();
        DOMFMA(0);
        BAR();

        // ---- P4 ----
        LDFRAGS(8192, 4);
        if (pf) {
            gld_lds16(b0 + 32, Ln + 24576 + dA);
            gld_lds16(b1 + 32, Ln + 24576 + dA + 512);
            SB0(); WAITVM(4); SB0();
        }
        BAR();
        DOMFMA(4);
        BAR();
    }

    float* dst = (z == 0) ? out : part1;
    const int rb = wr * 128 + (chunk << 2);
    const int cb = ntH * 256 + wc * 64 + lrow;
#pragma unroll
    for (int mf = 0; mf < 8; ++mf)
#pragma unroll
        for (int nf = 0; nf < 4; ++nf)
#pragma unroll
            for (int r2 = 0; r2 < 4; ++r2)
                dst[((size_t)b * SQ + rb + mf * 16 + r2) * HD + cb + nf * 16] = acc[mf][nf][r2];
}

// ---------------- combine: out += part1 ----------------
__global__ void combine_kernel(float* __restrict__ out,
                               const float* __restrict__ p1, int n4) {
    int i = blockIdx.x * 256 + threadIdx.x;
    if (i < n4) {
        float4 a = ((const float4*)out)[i];
        float4 c = ((const float4*)p1)[i];
        a.x += c.x; a.y += c.y; a.z += c.z; a.w += c.w;
        ((float4*)out)[i] = a;
    }
}

// ---------------- host ----------------
extern "C" void kernel_launch(void* const* d_in, const int* in_sizes, int n_in,
                              void* d_out, int out_size, void* d_ws, size_t ws_size,
                              hipStream_t stream) {
    const float* x        = (const float*)d_in[0];
    const float* logits   = (const float*)d_in[1];
    const float* sk_gate  = (const float*)d_in[2];
    const float* sk_up    = (const float*)d_in[3];
    const float* sk_down  = (const float*)d_in[4];
    const float* sh_gate  = (const float*)d_in[5];
    const float* sh_up    = (const float*)d_in[6];
    const float* sh_down  = (const float*)d_in[7];
    float* out = (float*)d_out;

    char* ws = (char*)d_ws;
    int*            eid   = (int*)(ws + OFF_EID);
    float*          wgt   = (float*)(ws + OFF_WGT);
    unsigned short* xbf   = (unsigned short*)(ws + OFF_XBF);
    unsigned short* gateT = (unsigned short*)(ws + OFF_GATET);
    unsigned short* upT   = (unsigned short*)(ws + OFF_UPT);
    unsigned short* downT = (unsigned short*)(ws + OFF_DOWNT);
    unsigned short* act   = (unsigned short*)(ws + OFF_ACT);
    float*          part1 = (float*)(ws + OFF_GATET);   // reuse dead gateT

    static int attr_set = 0;
    if (!attr_set) {
        hipFuncSetAttribute(reinterpret_cast<const void*>(stage1_gateup),
                            hipFuncAttributeMaxDynamicSharedMemorySize, 131072);
        hipFuncSetAttribute(reinterpret_cast<const void*>(stage2_down),
                            hipFuncAttributeMaxDynamicSharedMemorySize, 131072);
        attr_set = 1;
    }

    routing_kernel<<<1, 64, 0, stream>>>(logits, eid, wgt);

    const int n4 = (NB * SQ * HD) / 4;
    xcvt_kernel<<<(n4 + 255) / 256, 256, 0, stream>>>(x, xbf, n4);

    transpose_cvt<<<dim3(ID / 64, HD / 64, 9), 256, 0, stream>>>(sk_gate, sh_gate, gateT, HD, ID);
    transpose_cvt<<<dim3(ID / 64, HD / 64, 9), 256, 0, stream>>>(sk_up,   sh_up,   upT,   HD, ID);
    transpose_cvt<<<dim3(HD / 64, ID / 64, 9), 256, 0, stream>>>(sk_down, sh_down, downT, ID, HD);

    stage1_gateup<<<dim3(PAIRS * 32), 512, 131072, stream>>>(xbf, gateT, upT, eid, wgt, act);
    stage2_down<<<dim3(256), 512, 131072, stream>>>(act, downT, eid, out, part1);

    const int c4 = (NB * SQ * HD) / 4;
    combine_kernel<<<(c4 + 255) / 256, 256, 0, stream>>>(out, part1, c4);
}